// Round 1
// baseline (4780.107 us; speedup 1.0000x reference)
//
#include <hip/hip_runtime.h>

// PrimaryCaps: u[b,c,o] = sum_i x[b,c,i] * W[c,i,o] + bias[c,o]
// B=64, C=4096, IN=512, OUT=16. fp32. Memory-bound: ~688 MB ideal traffic.
//
// v2: coalesced LDS staging of x.
//  - Previous version read x rows in 16B nibbles at 8 MiB (power-of-2) stride:
//    L1/L2 set+channel aliasing re-fetched each line ~2.8x (FETCH=1.66GB vs
//    0.67GB ideal) and per-instruction distinct bytes were tiny (BW 39%).
//  - Now: 256 threads / capsule. x staged to LDS in K-chunks of 32 floats,
//    double-buffered. Staging wave reads 8 rows x 128B contiguous = 1KB/instr,
//    each line fetched once and fully consumed. 16 KiB LDS/block ->
//    8 blocks/CU -> 100% occupancy.
//  - LDS layout [64 rows][8 float4] with XOR swizzle (cj ^ (row&7)):
//    conflict-free 8-lane phases for both ds_write_b128 and ds_read_b128.
//  - W stays in global: sequential 32KB stream per block, 16-way broadcast,
//    L1 serves the block's 4 waves. Bias/output indexing unchanged.
//  - Per-thread k-accumulation order identical to v1 -> same numerics.

#define N_CAPS 4096
#define IN_DIM 512
#define OUT_DIM 16
#define BATCH 64
#define KC 32              // k floats per chunk
#define KC4 (KC / 4)       // 8 float4 per row per chunk
#define NCHUNK (IN_DIM / KC)  // 16

__device__ __forceinline__ void fma4(float4& a, float s, const float4& v) {
    a.x = fmaf(s, v.x, a.x);
    a.y = fmaf(s, v.y, a.y);
    a.z = fmaf(s, v.z, a.z);
    a.w = fmaf(s, v.w, a.w);
}

__global__ __launch_bounds__(256, 8)
void primary_caps_kernel(const float* __restrict__ x,
                         const float* __restrict__ W,
                         const float* __restrict__ bias,
                         float* __restrict__ out) {
    // double-buffered x chunk: [buf][row][cj4], XOR-swizzled on cj4
    __shared__ float4 xs[2][BATCH * KC4];   // 2 * 64 * 8 * 16B = 16 KiB

    const int c  = blockIdx.x;        // capsule
    const int t  = threadIdx.x;       // 0..255

    // compute role: one output row, 4 output cols
    const int b  = t >> 2;            // 0..63
    const int cg = t & 3;             // col group (4 cols)

    // staging role: rows {srow, srow+32}, float4-col scj within chunk
    const int srow = t >> 3;          // 0..31
    const int scj  = t & 7;           // 0..7

    const float4* x4 = (const float4*)x;
    const float4* W4 = (const float4*)W;
    const float4* b4 = (const float4*)bias;
    float4*       o4 = (float4*)out;

    // global staging pointers (float4 granularity); +KC4 per chunk
    const float4* sg0 = x4 + ((size_t)srow        * N_CAPS + c) * (IN_DIM / 4) + scj;
    const float4* sg1 = x4 + ((size_t)(srow + 32) * N_CAPS + c) * (IN_DIM / 4) + scj;

    // swizzled LDS write slots ((srow+32)&7 == srow&7)
    const int w0i = srow * KC4 + (scj ^ (srow & 7));
    const int w1i = w0i + 32 * KC4;

    // W pointer: float4 index = (c*512 + k)*4 + cg = c*2048 + k4*16 + cg
    const float4* wp = W4 + (size_t)c * (IN_DIM * OUT_DIM / 4) + cg;

    float4 acc = b4[(size_t)c * (OUT_DIM / 4) + cg];

    const int rbase = b * KC4;        // compute-read base
    const int rsw   = b & 7;          // read swizzle

    // prologue: stage chunk 0 into buf 0
    {
        float4 r0 = sg0[0];
        float4 r1 = sg1[0];
        xs[0][w0i] = r0;
        xs[0][w1i] = r1;
    }
    __syncthreads();

#pragma unroll 2
    for (int kc = 0; kc < NCHUNK; ++kc) {
        const int cur = kc & 1;

        // issue next-chunk global loads early (hide HBM under FMA phase)
        float4 n0, n1;
        const bool more = (kc + 1 < NCHUNK);
        if (more) {
            n0 = sg0[(size_t)(kc + 1) * KC4];
            n1 = sg1[(size_t)(kc + 1) * KC4];
        }

        // compute chunk kc from buf[cur]
        const float4* xb = &xs[cur][rbase];
        const float4* wk = wp + (size_t)kc * KC4 * 16;
#pragma unroll
        for (int i4 = 0; i4 < KC4; ++i4) {
            float4 wv0 = wk[i4 * 16 + 0];
            float4 wv1 = wk[i4 * 16 + 4];
            float4 wv2 = wk[i4 * 16 + 8];
            float4 wv3 = wk[i4 * 16 + 12];
            float4 xv  = xb[i4 ^ rsw];
            fma4(acc, xv.x, wv0);
            fma4(acc, xv.y, wv1);
            fma4(acc, xv.z, wv2);
            fma4(acc, xv.w, wv3);
        }

        // write next chunk after compute (loads have drained by now)
        if (more) {
            const int nxt = cur ^ 1;
            xs[nxt][w0i] = n0;
            xs[nxt][w1i] = n1;
        }
        __syncthreads();
    }

    // store: u[b, c, o] -> float4 index (b*C + c)*4 + cg
    o4[((size_t)b * N_CAPS + c) * (OUT_DIM / 4) + cg] = acc;
}

extern "C" void kernel_launch(void* const* d_in, const int* in_sizes, int n_in,
                              void* d_out, int out_size, void* d_ws, size_t ws_size,
                              hipStream_t stream) {
    const float* x    = (const float*)d_in[0];
    const float* W    = (const float*)d_in[1];
    const float* bias = (const float*)d_in[2];
    float*       out  = (float*)d_out;

    primary_caps_kernel<<<N_CAPS, 256, 0, stream>>>(x, W, bias, out);
}

// Round 2
// 1117.168 us; speedup vs baseline: 4.2788x; 4.2788x over previous
//
#include <hip/hip_runtime.h>

// PrimaryCaps: u[b,c,o] = sum_i x[b,c,i] * W[c,i,o] + bias[c,o]
// B=64, C=4096, IN=512, OUT=16. fp32. Memory-bound: ~656 MB ideal -> ~104 us floor.
//
// v3 = v1 structure (1 wave per capsule, no LDS, no barriers) + two fixes:
//  - v1 counters showed x over-fetched 2.8x: each wave keeps 16 live x lines
//    (8 MiB apart -> same L1 set) while streaming 32 KB of single-use W through
//    the same 32 KiB L1. Fix: W loads + out stores are NON-TEMPORAL (nt),
//    so the caches keep only x, whose lines need 8 temporal touches each.
//  - v1 occupancy was 37.75% (64-thread blocks hit the per-CU workgroup-slot
//    limit at 12 waves/CU -> only 39% of HBM BW). Fix: 256-thread blocks =
//    4 independent waves handling 4 consecutive capsules (no barrier, no LDS)
//    -> 8 blocks/CU = 32 waves/CU. Also makes the two 64B halves of each
//    128B output line (capsules c, c+1) come from the same block.
// Per-thread k-accumulation order and fmaf chain identical to v1 -> same numerics.

#define N_CAPS 4096
#define IN_DIM 512
#define OUT_DIM 16
#define BATCH 64
#define CAPS_PER_BLOCK 4

typedef float f4 __attribute__((ext_vector_type(4)));

__device__ __forceinline__ void fma4(f4& a, float s, const f4 v) {
    a.x = fmaf(s, v.x, a.x);
    a.y = fmaf(s, v.y, a.y);
    a.z = fmaf(s, v.z, a.z);
    a.w = fmaf(s, v.w, a.w);
}

__global__ __launch_bounds__(256, 8)
void primary_caps_kernel(const float* __restrict__ x,
                         const float* __restrict__ W,
                         const float* __restrict__ bias,
                         float* __restrict__ out) {
    const int wid = threadIdx.x >> 6;                    // wave in block: 0..3
    const int c   = blockIdx.x * CAPS_PER_BLOCK + wid;   // capsule
    const int t   = threadIdx.x & 63;                    // lane
    const int cg  = t & 3;                               // col group (4 cols)
    const int rg  = t >> 2;                              // row group

    const f4* x4 = (const f4*)x;
    const f4* W4 = (const f4*)W;
    const f4* b4 = (const f4*)bias;
    f4*       o4 = (f4*)out;

    // bias for this lane's 4 columns
    const f4 bv = b4[(size_t)c * (OUT_DIM / 4) + cg];
    f4 acc[4];
#pragma unroll
    for (int r = 0; r < 4; ++r) acc[r] = bv;

    // x row pointers (f4 granularity): x[b, c, :] contiguous, 512 floats
    const f4* xp[4];
#pragma unroll
    for (int r = 0; r < 4; ++r) {
        const size_t b = (size_t)(rg + 16 * r);
        xp[r] = x4 + (b * N_CAPS + c) * (IN_DIM / 4);
    }
    // W pointer: W[c, i, o]; f4 index = (c*512 + i)*4 + cg
    const f4* wp = W4 + (size_t)c * (IN_DIM * OUT_DIM / 4) + cg;

#pragma unroll 2
    for (int i4 = 0; i4 < IN_DIM / 4; ++i4) {
        // W rows k = 4*i4 .. 4*i4+3, this lane's 4 columns each.
        // Non-temporal: W is a single-use stream; keep it out of L1/L2
        // so the 16 live x lines per wave survive their 8 touches.
        f4 w0 = __builtin_nontemporal_load(wp + i4 * 16 + 0);
        f4 w1 = __builtin_nontemporal_load(wp + i4 * 16 + 4);
        f4 w2 = __builtin_nontemporal_load(wp + i4 * 16 + 8);
        f4 w3 = __builtin_nontemporal_load(wp + i4 * 16 + 12);
#pragma unroll
        for (int r = 0; r < 4; ++r) {
            const f4 xv = xp[r][i4];
            fma4(acc[r], xv.x, w0);
            fma4(acc[r], xv.y, w1);
            fma4(acc[r], xv.z, w2);
            fma4(acc[r], xv.w, w3);
        }
    }

    // store: u[b, c, o] -> f4 index (b*C + c)*4 + cg; single-use -> nt
#pragma unroll
    for (int r = 0; r < 4; ++r) {
        const size_t b = (size_t)(rg + 16 * r);
        __builtin_nontemporal_store(acc[r],
            &o4[(b * N_CAPS + c) * (OUT_DIM / 4) + cg]);
    }
}

extern "C" void kernel_launch(void* const* d_in, const int* in_sizes, int n_in,
                              void* d_out, int out_size, void* d_ws, size_t ws_size,
                              hipStream_t stream) {
    const float* x    = (const float*)d_in[0];
    const float* W    = (const float*)d_in[1];
    const float* bias = (const float*)d_in[2];
    float*       out  = (float*)d_out;

    primary_caps_kernel<<<N_CAPS / CAPS_PER_BLOCK, 256, 0, stream>>>(x, W, bias, out);
}

// Round 4
// 842.547 us; speedup vs baseline: 5.6734x; 1.3259x over previous
//
#include <hip/hip_runtime.h>

// PrimaryCaps: u[b,c,o] = sum_i x[b,c,i] * W[c,i,o] + bias[c,o]
// B=64, C=4096, IN=512, OUT=16. fp32. Ideal traffic ~688 MB -> ~110 us floor.
//
// v4 (resubmit — previous round failed on container infra, no measurement).
// v4 = v1 structure (1 wave / capsule, no LDS, no barriers) with ONE change:
// the x read path.
//  - v1/v3 counters: FETCH 1.66GB vs 0.69GB ideal. Cause: per i4-step a wave
//    held 64 live x lines (4 r-groups x 16 rows) at exact 8 MiB stride ->
//    single cache set, >> associativity -> thrash; each 16B touch re-missed
//    (x multiplier ~2.8). nt-hints were null (v3) because x thrashes ITSELF.
//  - Fix: the 4 lanes of a quad (same rg) no longer broadcast-read the same
//    16B word. They read 4 CONSECUTIVE float4s (quad covers 64B in one
//    instruction; the xa/xb pair covers a full 128B line back-to-back), then
//    exchange within the quad via __shfl(width=4) (quad_perm DPP, registers
//    only). Every x line is fetched once and fully consumed immediately ->
//    set aliasing can no longer cause re-fetch.
//  - Accumulation chain per acc[r] iterates i4=0..127 with w0..w3 exactly as
//    v1, on bit-identical xv values -> bit-identical output.
//  - W loads, stores, grid (4096 x 64) unchanged from v1.

#define N_CAPS 4096
#define IN_DIM 512
#define OUT_DIM 16
#define BATCH 64

typedef float f4 __attribute__((ext_vector_type(4)));

__device__ __forceinline__ void fma4(f4& a, float s, const f4 v) {
    a.x = fmaf(s, v.x, a.x);
    a.y = fmaf(s, v.y, a.y);
    a.z = fmaf(s, v.z, a.z);
    a.w = fmaf(s, v.w, a.w);
}

// broadcast lane j (0..3) of each quad to the whole quad, per component
__device__ __forceinline__ f4 quad_bcast(f4 v, int j) {
    f4 r;
    r.x = __shfl(v.x, j, 4);
    r.y = __shfl(v.y, j, 4);
    r.z = __shfl(v.z, j, 4);
    r.w = __shfl(v.w, j, 4);
    return r;
}

__global__ __launch_bounds__(64, 4)
void primary_caps_kernel(const float* __restrict__ x,
                         const float* __restrict__ W,
                         const float* __restrict__ bias,
                         float* __restrict__ out) {
    const int c  = blockIdx.x;        // capsule
    const int t  = threadIdx.x;       // 0..63
    const int cg = t & 3;             // col group (4 cols) / quad lane
    const int rg = t >> 2;            // row group (rows rg + 16*r)

    const f4* x4 = (const f4*)x;
    const f4* W4 = (const f4*)W;
    const f4* b4 = (const f4*)bias;
    f4*       o4 = (f4*)out;

    // bias for this lane's 4 columns
    const f4 bv = b4[(size_t)c * (OUT_DIM / 4) + cg];
    f4 acc[4];
#pragma unroll
    for (int r = 0; r < 4; ++r) acc[r] = bv;

    // x row pointers (f4 granularity): x[b, c, :] contiguous, 512 floats
    const f4* xp[4];
#pragma unroll
    for (int r = 0; r < 4; ++r) {
        const size_t b = (size_t)(rg + 16 * r);
        xp[r] = x4 + (b * N_CAPS + c) * (IN_DIM / 4);
    }
    // W pointer: W[c, i, o]; f4 index = (c*512 + i)*4 + cg
    const f4* wp = W4 + (size_t)c * (IN_DIM * OUT_DIM / 4) + cg;

    // macro-step m covers 32 floats of k (8 float4 = one 128B region per row)
    for (int m = 0; m < IN_DIM / 32; ++m) {
        // coalesced x loads: quad lanes cg=0..3 cover float4s [8m+cg] and
        // [8m+4+cg] -> two 64B segments = the full 128B line, back-to-back.
        f4 xa[4], xb[4];
#pragma unroll
        for (int r = 0; r < 4; ++r) {
            xa[r] = xp[r][m * 8 + cg];
            xb[r] = xp[r][m * 8 + 4 + cg];
        }
#pragma unroll
        for (int jj = 0; jj < 8; ++jj) {
            const int i4 = m * 8 + jj;   // same i4 sequence as v1
            f4 w0 = wp[i4 * 16 + 0];
            f4 w1 = wp[i4 * 16 + 4];
            f4 w2 = wp[i4 * 16 + 8];
            f4 w3 = wp[i4 * 16 + 12];
#pragma unroll
            for (int r = 0; r < 4; ++r) {
                // value this lane would have loaded itself in v1, via DPP
                const f4 xv = quad_bcast(jj < 4 ? xa[r] : xb[r], jj & 3);
                fma4(acc[r], xv.x, w0);
                fma4(acc[r], xv.y, w1);
                fma4(acc[r], xv.z, w2);
                fma4(acc[r], xv.w, w3);
            }
        }
    }

    // store: u[b, c, o] -> f4 index (b*C + c)*4 + cg (unchanged from v1)
#pragma unroll
    for (int r = 0; r < 4; ++r) {
        const size_t b = (size_t)(rg + 16 * r);
        o4[(b * N_CAPS + c) * (OUT_DIM / 4) + cg] = acc[r];
    }
}

extern "C" void kernel_launch(void* const* d_in, const int* in_sizes, int n_in,
                              void* d_out, int out_size, void* d_ws, size_t ws_size,
                              hipStream_t stream) {
    const float* x    = (const float*)d_in[0];
    const float* W    = (const float*)d_in[1];
    const float* bias = (const float*)d_in[2];
    float*       out  = (float*)d_out;

    primary_caps_kernel<<<N_CAPS, 64, 0, stream>>>(x, W, bias, out);
}